// Round 14
// baseline (284.587 us; speedup 1.0000x reference)
//
#include <hip/hip_runtime.h>
#include <math.h>

#define N_NODES 100000
#define N_EDGES 1600000
#define IN_CH 256
#define HID_CH 128
#define OUT_CH 64
#define NTILES ((N_NODES + 63) / 64)     // 1563 m-tiles of 64 rows
#define NB 1024                          // buckets: node >> 7
#define NPART 256                        // partition blocks
#define EPB (N_EDGES / NPART)            // 6250 edges per partition block
#define NB_USED ((N_NODES + 127) / 128)  // 782 buckets / gather node-blocks

typedef short s16x8 __attribute__((ext_vector_type(8)));
typedef unsigned short u16x8 __attribute__((ext_vector_type(8)));
typedef float f32x4 __attribute__((ext_vector_type(4)));

__device__ __forceinline__ float bf2f(unsigned short u) {
    union { unsigned int i; float f; } v;
    v.i = ((unsigned int)u) << 16;
    return v.f;
}
__device__ __forceinline__ unsigned short f2bf(float f) {
    union { float f; unsigned int i; } v;
    v.f = f;
    unsigned int u = v.i;
    return (unsigned short)((u + 0x7FFFu + ((u >> 16) & 1u)) >> 16);  // RNE
}

// ---------------- CSR build: LDS-histogram radix partition (no global atomics) ----------------

__global__ __launch_bounds__(256) void k_hist(const int* __restrict__ dst,
                                              int* __restrict__ ghist) {
    __shared__ int h[NB];
    int b = blockIdx.x, t = threadIdx.x;
    for (int k = t; k < NB; k += 256) h[k] = 0;
    __syncthreads();
    int e0 = b * EPB;
    for (int e = e0 + t; e < e0 + EPB; e += 256)
        atomicAdd(&h[dst[e] >> 7], 1);
    __syncthreads();
    for (int k = t; k < NB; k += 256) ghist[k * NPART + b] = h[k];
}

__global__ __launch_bounds__(256) void k_scan_cols(const int* __restrict__ ghist,
                                                   int* __restrict__ goff,
                                                   int* __restrict__ btot) {
    __shared__ int tmp[NPART];
    int k = blockIdx.x, t = threadIdx.x;
    int v = ghist[k * NPART + t];
    tmp[t] = v;
    __syncthreads();
    for (int off = 1; off < NPART; off <<= 1) {
        int u = (t >= off) ? tmp[t - off] : 0;
        __syncthreads();
        tmp[t] += u;
        __syncthreads();
    }
    goff[k * NPART + t] = tmp[t] - v;
    if (t == NPART - 1) btot[k] = tmp[t];
}

__global__ __launch_bounds__(1024) void k_scan_base(const int* __restrict__ btot,
                                                    int* __restrict__ bbase) {
    __shared__ int tmp[NB];
    int t = threadIdx.x;
    int v = btot[t];
    tmp[t] = v;
    __syncthreads();
    for (int off = 1; off < NB; off <<= 1) {
        int u = (t >= off) ? tmp[t - off] : 0;
        __syncthreads();
        tmp[t] += u;
        __syncthreads();
    }
    bbase[t] = tmp[t] - v;
    if (t == NB - 1) bbase[NB] = tmp[t];
}

__global__ __launch_bounds__(256) void k_partition(const int* __restrict__ src,
                                                   const int* __restrict__ dst,
                                                   const int* __restrict__ goff,
                                                   const int* __restrict__ bbase,
                                                   int2* __restrict__ bsorted) {
    __shared__ int cur[NB];
    int b = blockIdx.x, t = threadIdx.x;
    for (int k = t; k < NB; k += 256) cur[k] = bbase[k] + goff[k * NPART + b];
    __syncthreads();
    int e0 = b * EPB;
    for (int e = e0 + t; e < e0 + EPB; e += 256) {
        int s = src[e], d = dst[e];
        int pos = atomicAdd(&cur[d >> 7], 1);
        bsorted[pos] = make_int2(s, d);
    }
}

__global__ __launch_bounds__(256) void k_bucket_csr(const int2* __restrict__ bsorted,
                                                    const int* __restrict__ bbase,
                                                    int* __restrict__ rowoff,
                                                    float* __restrict__ dinv,
                                                    int* __restrict__ csr_src) {
    __shared__ int cnt[128];
    __shared__ int tmp[256];
    __shared__ int cur[128];
    int b = blockIdx.x, t = threadIdx.x;
    int ebeg = bbase[b], eend = bbase[b + 1];
    if (t < 128) cnt[t] = 0;
    __syncthreads();
    for (int e = ebeg + t; e < eend; e += 256)
        atomicAdd(&cnt[bsorted[e].y & 127], 1);
    __syncthreads();
    int v = (t < 128) ? cnt[t] : 0;
    tmp[t] = v;
    __syncthreads();
    for (int off = 1; off < 256; off <<= 1) {
        int u = (t >= off) ? tmp[t - off] : 0;
        __syncthreads();
        tmp[t] += u;
        __syncthreads();
    }
    if (t < 128) {
        int base = ebeg + tmp[t] - v;
        cur[t] = base;
        int node = b * 128 + t;
        if (node < N_NODES) {
            rowoff[node] = base;
            dinv[node] = rsqrtf((float)v + 1.0f);
        }
    }
    __syncthreads();
    for (int e = ebeg + t; e < eend; e += 256) {
        int2 ed = bsorted[e];
        int pos = atomicAdd(&cur[ed.y & 127], 1);
        csr_src[pos] = ed.x;
    }
}

// ---------------- streaming cast: xb = bf16(x), fully contiguous ----------------
__global__ __launch_bounds__(256) void k_cast(const float* __restrict__ x,
                                              unsigned short* __restrict__ xb) {
    const int total = N_NODES * IN_CH / 8;
    int stride = gridDim.x * 256;
    for (int i = blockIdx.x * 256 + threadIdx.x; i < total; i += stride) {
        f32x4 a = *reinterpret_cast<const f32x4*>(x + (size_t)i * 8);
        f32x4 b = *reinterpret_cast<const f32x4*>(x + (size_t)i * 8 + 4);
        u16x8 o;
        o[0] = f2bf(a[0]); o[1] = f2bf(a[1]); o[2] = f2bf(a[2]); o[3] = f2bf(a[3]);
        o[4] = f2bf(b[0]); o[5] = f2bf(b[1]); o[6] = f2bf(b[2]); o[7] = f2bf(b[3]);
        *reinterpret_cast<u16x8*>(xb + (size_t)i * 8) = o;
    }
}

// ---------------- W -> fragment-linear bf16 layout ----------------
__global__ void k_wt1(const float* __restrict__ W1, unsigned short* __restrict__ Wf1) {
    int u = blockIdx.x * 256 + threadIdx.x;
    int f = u >> 6, lane = u & 63;
    int kk = f >> 3, nt = f & 7;
    int l15 = lane & 15, lhi = lane >> 4;
    int n = nt * 16 + l15;
    int kbase = kk * 32 + lhi * 8;
    #pragma unroll
    for (int j = 0; j < 8; ++j)
        Wf1[(size_t)u * 8 + j] = f2bf(W1[(size_t)(kbase + j) * HID_CH + n]);
}

__global__ void k_wt2(const float* __restrict__ W2, unsigned short* __restrict__ Wf2) {
    int u = blockIdx.x * 256 + threadIdx.x;
    int f = u >> 6, lane = u & 63;
    int kk = f >> 2, nt = f & 3;
    int l15 = lane & 15, lhi = lane >> 4;
    int n = nt * 16 + l15;
    int kbase = kk * 32 + lhi * 8;
    #pragma unroll
    for (int j = 0; j < 8; ++j)
        Wf2[(size_t)u * 8 + j] = f2bf(W2[(size_t)(kbase + j) * OUT_CH + n]);
}

// ---------------- GEMM1: channel-sliced output hs1s[p][row][16], p = nt ----------------
__global__ __launch_bounds__(256, 4) void k_gemm1(const unsigned short* __restrict__ xb,
                                                  const unsigned short* __restrict__ Wf1,
                                                  const float* __restrict__ dinv,
                                                  unsigned short* __restrict__ hs1s) {
    int tid = threadIdx.x;
    int w = tid >> 6;
    int lane = tid & 63;
    int l15 = lane & 15;
    int lhi = lane >> 4;
    int m0 = blockIdx.x * 64;

    int arow = m0 + w * 16 + l15;
    int arowc = (arow < N_NODES) ? arow : (N_NODES - 1);
    const s16x8* ap = reinterpret_cast<const s16x8*>(xb + (size_t)arowc * IN_CH) + lhi;

    s16x8 af[8];
    #pragma unroll
    for (int kk = 0; kk < 8; ++kk) af[kk] = ap[kk * 4];

    const s16x8* wp = reinterpret_cast<const s16x8*>(Wf1) + lane;

    f32x4 acc[8] = {};
    #pragma unroll
    for (int kk = 0; kk < 8; ++kk) {
        #pragma unroll
        for (int nt = 0; nt < 8; ++nt) {
            s16x8 bf = wp[(kk * 8 + nt) * 64];
            acc[nt] = __builtin_amdgcn_mfma_f32_16x16x32_bf16(af[kk], bf, acc[nt], 0, 0, 0);
        }
    }

    float dv[4];
    int rb = m0 + w * 16 + lhi * 4;
    #pragma unroll
    for (int r = 0; r < 4; ++r) dv[r] = (rb + r < N_NODES) ? dinv[rb + r] : 0.0f;
    #pragma unroll
    for (int nt = 0; nt < 8; ++nt) {
        #pragma unroll
        for (int r = 0; r < 4; ++r) {
            int row = rb + r;
            if (row < N_NODES)
                hs1s[((size_t)nt * N_NODES + row) * 16 + l15] = f2bf(dv[r] * acc[nt][r]);
        }
    }
}

// ---------------- gather1: XCD-pinned channel-plane aggregation ----------------
// Grid 8*782 1D. plane = blockIdx&7 -> lands on XCD (blockIdx&7) by HW round-robin.
// Each XCD touches ONLY its 3.2MB plane of hs1s (fits 4MB L2) -> compulsory misses only.
// 2 lanes/node x 16B, unroll-4. Output h1rs[p][node][16] (relu'd), coalesced 32B/node.
__global__ __launch_bounds__(256) void k_gather_sx1(const int* __restrict__ rowoff,
                                                    const int* __restrict__ csr_src,
                                                    const unsigned short* __restrict__ hs1s,
                                                    const float* __restrict__ dinv,
                                                    const float* __restrict__ b1,
                                                    unsigned short* __restrict__ h1rs) {
    int b = blockIdx.x;
    int p = b & 7;          // plane == XCD
    int idx = b >> 3;       // 0..781
    int t = threadIdx.x;
    int node = idx * 128 + (t >> 1);
    int q = t & 1;          // 8-channel half of the 16ch plane slice
    if (node >= N_NODES) return;

    const unsigned short* P = hs1s + (size_t)p * N_NODES * 16 + q * 8;

    int beg = rowoff[node];
    int end = (node + 1 < N_NODES) ? rowoff[node + 1] : N_EDGES;

    float acc[8];
    {
        u16x8 sv = *reinterpret_cast<const u16x8*>(P + (size_t)node * 16);
        #pragma unroll
        for (int c = 0; c < 8; ++c) acc[c] = bf2f(sv[c]);
    }

    int i = beg;
    for (; i + 3 < end; i += 4) {
        int s0 = csr_src[i], s1 = csr_src[i + 1], s2 = csr_src[i + 2], s3 = csr_src[i + 3];
        u16x8 v0 = *reinterpret_cast<const u16x8*>(P + (size_t)s0 * 16);
        u16x8 v1 = *reinterpret_cast<const u16x8*>(P + (size_t)s1 * 16);
        u16x8 v2 = *reinterpret_cast<const u16x8*>(P + (size_t)s2 * 16);
        u16x8 v3 = *reinterpret_cast<const u16x8*>(P + (size_t)s3 * 16);
        #pragma unroll
        for (int c = 0; c < 8; ++c)
            acc[c] += (bf2f(v0[c]) + bf2f(v1[c])) + (bf2f(v2[c]) + bf2f(v3[c]));
    }
    for (; i < end; ++i) {
        int s0 = csr_src[i];
        u16x8 v0 = *reinterpret_cast<const u16x8*>(P + (size_t)s0 * 16);
        #pragma unroll
        for (int c = 0; c < 8; ++c) acc[c] += bf2f(v0[c]);
    }

    float w = dinv[node];
    float4 ba = *reinterpret_cast<const float4*>(b1 + p * 16 + q * 8);
    float4 bb = *reinterpret_cast<const float4*>(b1 + p * 16 + q * 8 + 4);
    float bv[8] = {ba.x, ba.y, ba.z, ba.w, bb.x, bb.y, bb.z, bb.w};
    u16x8 o;
    #pragma unroll
    for (int c = 0; c < 8; ++c)
        o[c] = f2bf(fmaxf(w * acc[c] + bv[c], 0.0f));
    *reinterpret_cast<u16x8*>(h1rs + ((size_t)p * N_NODES + node) * 16 + q * 8) = o;
}

// ---------------- GEMM2: A from sliced h1rs, standard hs2 out ----------------
__global__ __launch_bounds__(256, 4) void k_gemm2(const unsigned short* __restrict__ h1rs,
                                                  const unsigned short* __restrict__ Wf2,
                                                  const float* __restrict__ dinv,
                                                  unsigned short* __restrict__ hs2) {
    int tid = threadIdx.x;
    int w = tid >> 6;
    int lane = tid & 63;
    int l15 = lane & 15;
    int lhi = lane >> 4;
    int m0 = blockIdx.x * 64;

    int arow = m0 + w * 16 + l15;
    int arowc = (arow < N_NODES) ? arow : (N_NODES - 1);

    // channels kk*32 + lhi*8 + [0,8) live in plane 2kk+(lhi>>1), offset (lhi&1)*8
    s16x8 af[4];
    #pragma unroll
    for (int kk = 0; kk < 4; ++kk) {
        int plane = 2 * kk + (lhi >> 1);
        af[kk] = *reinterpret_cast<const s16x8*>(
            h1rs + ((size_t)plane * N_NODES + arowc) * 16 + (lhi & 1) * 8);
    }

    const s16x8* wp = reinterpret_cast<const s16x8*>(Wf2) + lane;
    f32x4 acc[4] = {};
    #pragma unroll
    for (int kk = 0; kk < 4; ++kk) {
        #pragma unroll
        for (int nt = 0; nt < 4; ++nt) {
            s16x8 bf = wp[(kk * 4 + nt) * 64];
            acc[nt] = __builtin_amdgcn_mfma_f32_16x16x32_bf16(af[kk], bf, acc[nt], 0, 0, 0);
        }
    }

    float dv[4];
    int rb = m0 + w * 16 + lhi * 4;
    #pragma unroll
    for (int r = 0; r < 4; ++r) dv[r] = (rb + r < N_NODES) ? dinv[rb + r] : 0.0f;
    #pragma unroll
    for (int nt = 0; nt < 4; ++nt) {
        #pragma unroll
        for (int r = 0; r < 4; ++r) {
            int row = rb + r;
            if (row < N_NODES)
                hs2[(size_t)row * OUT_CH + nt * 16 + l15] = f2bf(dv[r] * acc[nt][r]);
        }
    }
}

// ---------------- gather aggregation (standard layout, unroll-4) ----------------
template <int C, bool RELU>
__global__ __launch_bounds__(256) void k_gather_agg(const int* __restrict__ rowoff,
                                                    const int* __restrict__ csr_src,
                                                    const unsigned short* __restrict__ hs,
                                                    const float* __restrict__ dinv,
                                                    const float* __restrict__ b,
                                                    unsigned short* __restrict__ outp) {
    constexpr int TPN = C / 8;
    constexpr int NPB = 256 / TPN;
    int t = threadIdx.x;
    int node = blockIdx.x * NPB + t / TPN;
    int q = t % TPN;
    if (node >= N_NODES) return;

    int beg = rowoff[node];
    int end = (node + 1 < N_NODES) ? rowoff[node + 1] : N_EDGES;

    float acc[8];
    {
        u16x8 sv = *reinterpret_cast<const u16x8*>(&hs[(size_t)node * C + q * 8]);
        #pragma unroll
        for (int j = 0; j < 8; ++j) acc[j] = bf2f(sv[j]);
    }

    int i = beg;
    for (; i + 3 < end; i += 4) {
        int s0 = csr_src[i], s1 = csr_src[i + 1], s2 = csr_src[i + 2], s3 = csr_src[i + 3];
        u16x8 v0 = *reinterpret_cast<const u16x8*>(&hs[(size_t)s0 * C + q * 8]);
        u16x8 v1 = *reinterpret_cast<const u16x8*>(&hs[(size_t)s1 * C + q * 8]);
        u16x8 v2 = *reinterpret_cast<const u16x8*>(&hs[(size_t)s2 * C + q * 8]);
        u16x8 v3 = *reinterpret_cast<const u16x8*>(&hs[(size_t)s3 * C + q * 8]);
        #pragma unroll
        for (int j = 0; j < 8; ++j)
            acc[j] += (bf2f(v0[j]) + bf2f(v1[j])) + (bf2f(v2[j]) + bf2f(v3[j]));
    }
    for (; i < end; ++i) {
        int s0 = csr_src[i];
        u16x8 v0 = *reinterpret_cast<const u16x8*>(&hs[(size_t)s0 * C + q * 8]);
        #pragma unroll
        for (int j = 0; j < 8; ++j) acc[j] += bf2f(v0[j]);
    }

    float w = dinv[node];
    float4 b0 = reinterpret_cast<const float4*>(b)[q * 2];
    float4 b1 = reinterpret_cast<const float4*>(b)[q * 2 + 1];
    float bb[8] = {b0.x, b0.y, b0.z, b0.w, b1.x, b1.y, b1.z, b1.w};
    u16x8 o;
    #pragma unroll
    for (int j = 0; j < 8; ++j) {
        float v = w * acc[j] + bb[j];
        if (RELU) v = fmaxf(v, 0.0f);
        o[j] = f2bf(v);
    }
    *reinterpret_cast<u16x8*>(&outp[(size_t)node * C + q * 8]) = o;
}

// ---------------- decoder ----------------

__global__ __launch_bounds__(256) void k_decode(const int* __restrict__ esrc,
                                                const int* __restrict__ edst,
                                                const unsigned short* __restrict__ z,
                                                float* __restrict__ out) {
    int tid = threadIdx.x;
    int e = blockIdx.x * 32 + tid / 8;
    int q = tid % 8;
    if (e >= N_EDGES) return;
    int s = esrc[e], d = edst[e];
    u16x8 a = *reinterpret_cast<const u16x8*>(&z[(size_t)s * OUT_CH + q * 8]);
    u16x8 b = *reinterpret_cast<const u16x8*>(&z[(size_t)d * OUT_CH + q * 8]);
    float dot = 0.0f;
    #pragma unroll
    for (int j = 0; j < 8; ++j) dot += bf2f(a[j]) * bf2f(b[j]);
    dot += __shfl_xor(dot, 1);
    dot += __shfl_xor(dot, 2);
    dot += __shfl_xor(dot, 4);
    if (q == 0) out[e] = 1.0f / (1.0f + expf(-dot));
}

// ---------------- launch ----------------

extern "C" void kernel_launch(void* const* d_in, const int* in_sizes, int n_in,
                              void* d_out, int out_size, void* d_ws, size_t ws_size,
                              hipStream_t stream) {
    const float* x  = (const float*)d_in[0];
    const int*   ei = (const int*)d_in[1];
    const float* W1 = (const float*)d_in[2];
    const float* b1 = (const float*)d_in[3];
    const float* W2 = (const float*)d_in[4];
    const float* b2 = (const float*)d_in[5];
    float* out = (float*)d_out;

    const int* src = ei;
    const int* dst = ei + N_EDGES;

    // workspace layout; overlays exploit liveness:
    //   bsorted dead after k_bucket_csr -> xb overlays it
    //   xb dead after k_gemm1 -> h1rs/hs2 overlay it
    //   hs1s dead after k_gather_sx1 -> z overlays it
    char* ws = (char*)d_ws;
    int*   ghist   = (int*)(ws + 0x000000);       // 1 MB
    int*   goff    = (int*)(ws + 0x100000);       // 1 MB
    int*   btot    = (int*)(ws + 0x200000);       // 4 KB
    int*   bbase   = (int*)(ws + 0x202000);       // 4.1 KB
    int*   rowoff  = (int*)(ws + 0x210000);       // 400 KB
    float* dinv    = (float*)(ws + 0x290000);     // 400 KB
    unsigned short* Wf1 = (unsigned short*)(ws + 0x310000);   // 64 KB frag-linear
    unsigned short* Wf2 = (unsigned short*)(ws + 0x320000);   // 16 KB frag-linear
    int*   csr_src = (int*)(ws + 0x400000);       // 6.4 MB
    int2*  bsorted = (int2*)(ws + 0xB00000);      // 12.8 MB (dead after CSR build)
    unsigned short* xb   = (unsigned short*)(ws + 0xB00000);   // 51.2 MB (dead after gemm1)
    unsigned short* hs1s = (unsigned short*)(ws + 0x3C00000);  // 25.6 MB, 8 planes
    unsigned short* h1rs = (unsigned short*)(ws + 0xB00000);   // 25.6 MB (over dead xb)
    unsigned short* hs2  = (unsigned short*)(ws + 0x2800000);  // 12.8 MB (over dead xb tail)
    unsigned short* z    = (unsigned short*)(ws + 0x3C00000);  // 12.8 MB (over dead hs1s)

    // --- CSR build (no global atomics) ---
    k_hist<<<NPART, 256, 0, stream>>>(dst, ghist);
    k_scan_cols<<<NB, 256, 0, stream>>>(ghist, goff, btot);
    k_scan_base<<<1, NB, 0, stream>>>(btot, bbase);
    k_partition<<<NPART, 256, 0, stream>>>(src, dst, goff, bbase, bsorted);
    k_bucket_csr<<<NB_USED, 256, 0, stream>>>(bsorted, bbase, rowoff, dinv, csr_src);

    // --- x cast + weight fragment layout ---
    k_cast<<<2048, 256, 0, stream>>>(x, xb);
    k_wt1<<<16, 256, 0, stream>>>(W1, Wf1);
    k_wt2<<<4, 256, 0, stream>>>(W2, Wf2);

    // --- layer 1: GEMM (sliced out) + XCD-pinned plane gather ---
    k_gemm1<<<NTILES, 256, 0, stream>>>(xb, Wf1, dinv, hs1s);
    k_gather_sx1<<<8 * NB_USED, 256, 0, stream>>>(rowoff, csr_src, hs1s, dinv, b1, h1rs);

    // --- layer 2: GEMM (sliced A) + standard gather ---
    k_gemm2<<<NTILES, 256, 0, stream>>>(h1rs, Wf2, dinv, hs2);
    k_gather_agg<OUT_CH, false><<<(N_NODES * 8 + 255) / 256, 256, 0, stream>>>(
        rowoff, csr_src, hs2, dinv, b2, z);

    // --- decoder ---
    k_decode<<<N_EDGES / 32, 256, 0, stream>>>(src, dst, z, out);
}

// Round 15
// 281.554 us; speedup vs baseline: 1.0108x; 1.0108x over previous
//
#include <hip/hip_runtime.h>
#include <math.h>

#define N_NODES 100000
#define N_EDGES 1600000
#define IN_CH 256
#define HID_CH 128
#define OUT_CH 64
#define NTILES ((N_NODES + 63) / 64)     // 1563 m-tiles of 64 rows
#define NB 1024                          // buckets: node >> 7
#define NPART 256                        // partition blocks
#define EPB (N_EDGES / NPART)            // 6250 edges per partition block
#define NB_USED ((N_NODES + 127) / 128)  // 782 buckets
#define NORD (NB_USED * 128)             // 100096 nodeord slots

typedef short s16x8 __attribute__((ext_vector_type(8)));
typedef unsigned short u16x8 __attribute__((ext_vector_type(8)));
typedef float f32x4 __attribute__((ext_vector_type(4)));

__device__ __forceinline__ float bf2f(unsigned short u) {
    union { unsigned int i; float f; } v;
    v.i = ((unsigned int)u) << 16;
    return v.f;
}
__device__ __forceinline__ unsigned short f2bf(float f) {
    union { float f; unsigned int i; } v;
    v.f = f;
    unsigned int u = v.i;
    return (unsigned short)((u + 0x7FFFu + ((u >> 16) & 1u)) >> 16);  // RNE
}

// ---------------- CSR build: LDS-histogram radix partition (no global atomics) ----------------

__global__ __launch_bounds__(256) void k_hist(const int* __restrict__ dst,
                                              int* __restrict__ ghist) {
    __shared__ int h[NB];
    int b = blockIdx.x, t = threadIdx.x;
    for (int k = t; k < NB; k += 256) h[k] = 0;
    __syncthreads();
    int e0 = b * EPB;
    for (int e = e0 + t; e < e0 + EPB; e += 256)
        atomicAdd(&h[dst[e] >> 7], 1);
    __syncthreads();
    for (int k = t; k < NB; k += 256) ghist[k * NPART + b] = h[k];
}

__global__ __launch_bounds__(256) void k_scan_cols(const int* __restrict__ ghist,
                                                   int* __restrict__ goff,
                                                   int* __restrict__ btot) {
    __shared__ int tmp[NPART];
    int k = blockIdx.x, t = threadIdx.x;
    int v = ghist[k * NPART + t];
    tmp[t] = v;
    __syncthreads();
    for (int off = 1; off < NPART; off <<= 1) {
        int u = (t >= off) ? tmp[t - off] : 0;
        __syncthreads();
        tmp[t] += u;
        __syncthreads();
    }
    goff[k * NPART + t] = tmp[t] - v;
    if (t == NPART - 1) btot[k] = tmp[t];
}

__global__ __launch_bounds__(1024) void k_scan_base(const int* __restrict__ btot,
                                                    int* __restrict__ bbase) {
    __shared__ int tmp[NB];
    int t = threadIdx.x;
    int v = btot[t];
    tmp[t] = v;
    __syncthreads();
    for (int off = 1; off < NB; off <<= 1) {
        int u = (t >= off) ? tmp[t - off] : 0;
        __syncthreads();
        tmp[t] += u;
        __syncthreads();
    }
    bbase[t] = tmp[t] - v;
    if (t == NB - 1) bbase[NB] = tmp[t];
}

__global__ __launch_bounds__(256) void k_partition(const int* __restrict__ src,
                                                   const int* __restrict__ dst,
                                                   const int* __restrict__ goff,
                                                   const int* __restrict__ bbase,
                                                   int2* __restrict__ bsorted) {
    __shared__ int cur[NB];
    int b = blockIdx.x, t = threadIdx.x;
    for (int k = t; k < NB; k += 256) cur[k] = bbase[k] + goff[k * NPART + b];
    __syncthreads();
    int e0 = b * EPB;
    for (int e = e0 + t; e < e0 + EPB; e += 256) {
        int s = src[e], d = dst[e];
        int pos = atomicAdd(&cur[d >> 7], 1);
        bsorted[pos] = make_int2(s, d);
    }
}

// Also emits nodeord: per-bucket descending-degree counting-rank permutation,
// so gather waves process degree-similar nodes (kills max-of-4 divergence).
__global__ __launch_bounds__(256) void k_bucket_csr(const int2* __restrict__ bsorted,
                                                    const int* __restrict__ bbase,
                                                    int* __restrict__ rowoff,
                                                    float* __restrict__ dinv,
                                                    int* __restrict__ csr_src,
                                                    int* __restrict__ nodeord) {
    __shared__ int cnt[128];
    __shared__ int tmp[256];
    __shared__ int cur[128];
    int b = blockIdx.x, t = threadIdx.x;
    int ebeg = bbase[b], eend = bbase[b + 1];
    if (t < 128) cnt[t] = 0;
    __syncthreads();
    for (int e = ebeg + t; e < eend; e += 256)
        atomicAdd(&cnt[bsorted[e].y & 127], 1);
    __syncthreads();
    int v = (t < 128) ? cnt[t] : 0;
    tmp[t] = v;
    __syncthreads();
    for (int off = 1; off < 256; off <<= 1) {
        int u = (t >= off) ? tmp[t - off] : 0;
        __syncthreads();
        tmp[t] += u;
        __syncthreads();
    }
    if (t < 128) {
        int base = ebeg + tmp[t] - v;
        cur[t] = base;
        int node = b * 128 + t;
        if (node < N_NODES) {
            rowoff[node] = base;
            dinv[node] = rsqrtf((float)v + 1.0f);
        }
        // degree-rank (descending; ties by index). invalid nodes have deg 0 -> tail.
        int myd = cnt[t];
        int rank = 0;
        for (int j = 0; j < 128; ++j) {
            int dj = cnt[j];
            rank += ((dj > myd) || (dj == myd && j < t)) ? 1 : 0;
        }
        nodeord[b * 128 + rank] = node;
    }
    __syncthreads();
    for (int e = ebeg + t; e < eend; e += 256) {
        int2 ed = bsorted[e];
        int pos = atomicAdd(&cur[ed.y & 127], 1);
        csr_src[pos] = ed.x;
    }
}

// ---------------- streaming cast: xb = bf16(x), fully contiguous ----------------
__global__ __launch_bounds__(256) void k_cast(const float* __restrict__ x,
                                              unsigned short* __restrict__ xb) {
    const int total = N_NODES * IN_CH / 8;
    int stride = gridDim.x * 256;
    for (int i = blockIdx.x * 256 + threadIdx.x; i < total; i += stride) {
        f32x4 a = *reinterpret_cast<const f32x4*>(x + (size_t)i * 8);
        f32x4 b = *reinterpret_cast<const f32x4*>(x + (size_t)i * 8 + 4);
        u16x8 o;
        o[0] = f2bf(a[0]); o[1] = f2bf(a[1]); o[2] = f2bf(a[2]); o[3] = f2bf(a[3]);
        o[4] = f2bf(b[0]); o[5] = f2bf(b[1]); o[6] = f2bf(b[2]); o[7] = f2bf(b[3]);
        *reinterpret_cast<u16x8*>(xb + (size_t)i * 8) = o;
    }
}

// ---------------- W -> fragment-linear bf16 layout ----------------
__global__ void k_wt1(const float* __restrict__ W1, unsigned short* __restrict__ Wf1) {
    int u = blockIdx.x * 256 + threadIdx.x;
    int f = u >> 6, lane = u & 63;
    int kk = f >> 3, nt = f & 7;
    int l15 = lane & 15, lhi = lane >> 4;
    int n = nt * 16 + l15;
    int kbase = kk * 32 + lhi * 8;
    #pragma unroll
    for (int j = 0; j < 8; ++j)
        Wf1[(size_t)u * 8 + j] = f2bf(W1[(size_t)(kbase + j) * HID_CH + n]);
}

__global__ void k_wt2(const float* __restrict__ W2, unsigned short* __restrict__ Wf2) {
    int u = blockIdx.x * 256 + threadIdx.x;
    int f = u >> 6, lane = u & 63;
    int kk = f >> 2, nt = f & 3;
    int l15 = lane & 15, lhi = lane >> 4;
    int n = nt * 16 + l15;
    int kbase = kk * 32 + lhi * 8;
    #pragma unroll
    for (int j = 0; j < 8; ++j)
        Wf2[(size_t)u * 8 + j] = f2bf(W2[(size_t)(kbase + j) * OUT_CH + n]);
}

// ---------------- GEMM1: hs1[m][n] = bf16( dinv[m] * sum_k xb[m][k] W1[k][n] ) ----------------
__global__ __launch_bounds__(256, 4) void k_gemm1(const unsigned short* __restrict__ xb,
                                                  const unsigned short* __restrict__ Wf1,
                                                  const float* __restrict__ dinv,
                                                  unsigned short* __restrict__ hs1) {
    int tid = threadIdx.x;
    int w = tid >> 6;
    int lane = tid & 63;
    int l15 = lane & 15;
    int lhi = lane >> 4;
    int m0 = blockIdx.x * 64;

    int arow = m0 + w * 16 + l15;
    int arowc = (arow < N_NODES) ? arow : (N_NODES - 1);
    const s16x8* ap = reinterpret_cast<const s16x8*>(xb + (size_t)arowc * IN_CH) + lhi;

    s16x8 af[8];
    #pragma unroll
    for (int kk = 0; kk < 8; ++kk) af[kk] = ap[kk * 4];

    const s16x8* wp = reinterpret_cast<const s16x8*>(Wf1) + lane;

    f32x4 acc[8] = {};
    #pragma unroll
    for (int kk = 0; kk < 8; ++kk) {
        #pragma unroll
        for (int nt = 0; nt < 8; ++nt) {
            s16x8 bf = wp[(kk * 8 + nt) * 64];
            acc[nt] = __builtin_amdgcn_mfma_f32_16x16x32_bf16(af[kk], bf, acc[nt], 0, 0, 0);
        }
    }

    float dv[4];
    int rb = m0 + w * 16 + lhi * 4;
    #pragma unroll
    for (int r = 0; r < 4; ++r) dv[r] = (rb + r < N_NODES) ? dinv[rb + r] : 0.0f;
    #pragma unroll
    for (int nt = 0; nt < 8; ++nt) {
        #pragma unroll
        for (int r = 0; r < 4; ++r) {
            int row = rb + r;
            if (row < N_NODES)
                hs1[(size_t)row * HID_CH + nt * 16 + l15] = f2bf(dv[r] * acc[nt][r]);
        }
    }
}

// ---------------- GEMM2: hs2[m][n] = bf16( dinv[m] * sum_k h1r[m][k] W2[k][n] ) ----------------
__global__ __launch_bounds__(256, 4) void k_gemm2(const unsigned short* __restrict__ h1r,
                                                  const unsigned short* __restrict__ Wf2,
                                                  const float* __restrict__ dinv,
                                                  unsigned short* __restrict__ hs2) {
    int tid = threadIdx.x;
    int w = tid >> 6;
    int lane = tid & 63;
    int l15 = lane & 15;
    int lhi = lane >> 4;
    int m0 = blockIdx.x * 64;

    int arow = m0 + w * 16 + l15;
    int arowc = (arow < N_NODES) ? arow : (N_NODES - 1);
    const s16x8* ap = reinterpret_cast<const s16x8*>(h1r + (size_t)arowc * HID_CH) + lhi;

    s16x8 af[4];
    #pragma unroll
    for (int kk = 0; kk < 4; ++kk) af[kk] = ap[kk * 4];

    const s16x8* wp = reinterpret_cast<const s16x8*>(Wf2) + lane;

    f32x4 acc[4] = {};
    #pragma unroll
    for (int kk = 0; kk < 4; ++kk) {
        #pragma unroll
        for (int nt = 0; nt < 4; ++nt) {
            s16x8 bf = wp[(kk * 4 + nt) * 64];
            acc[nt] = __builtin_amdgcn_mfma_f32_16x16x32_bf16(af[kk], bf, acc[nt], 0, 0, 0);
        }
    }

    float dv[4];
    int rb = m0 + w * 16 + lhi * 4;
    #pragma unroll
    for (int r = 0; r < 4; ++r) dv[r] = (rb + r < N_NODES) ? dinv[rb + r] : 0.0f;
    #pragma unroll
    for (int nt = 0; nt < 4; ++nt) {
        #pragma unroll
        for (int r = 0; r < 4; ++r) {
            int row = rb + r;
            if (row < N_NODES)
                hs2[(size_t)row * OUT_CH + nt * 16 + l15] = f2bf(dv[r] * acc[nt][r]);
        }
    }
}

// ---------------- gather aggregation via degree-ranked nodeord ----------------
template <int C, bool RELU>
__global__ __launch_bounds__(256) void k_gather_agg(const int* __restrict__ nodeord,
                                                    const int* __restrict__ rowoff,
                                                    const int* __restrict__ csr_src,
                                                    const unsigned short* __restrict__ hs,
                                                    const float* __restrict__ dinv,
                                                    const float* __restrict__ b,
                                                    unsigned short* __restrict__ outp) {
    constexpr int TPN = C / 8;
    constexpr int NPB = 256 / TPN;
    int t = threadIdx.x;
    int node = nodeord[blockIdx.x * NPB + t / TPN];
    int q = t % TPN;
    if (node >= N_NODES) return;

    int beg = rowoff[node];
    int end = (node + 1 < N_NODES) ? rowoff[node + 1] : N_EDGES;

    float acc[8];
    {
        u16x8 sv = *reinterpret_cast<const u16x8*>(&hs[(size_t)node * C + q * 8]);
        #pragma unroll
        for (int j = 0; j < 8; ++j) acc[j] = bf2f(sv[j]);
    }

    int i = beg;
    for (; i + 3 < end; i += 4) {
        int s0 = csr_src[i], s1 = csr_src[i + 1], s2 = csr_src[i + 2], s3 = csr_src[i + 3];
        u16x8 v0 = *reinterpret_cast<const u16x8*>(&hs[(size_t)s0 * C + q * 8]);
        u16x8 v1 = *reinterpret_cast<const u16x8*>(&hs[(size_t)s1 * C + q * 8]);
        u16x8 v2 = *reinterpret_cast<const u16x8*>(&hs[(size_t)s2 * C + q * 8]);
        u16x8 v3 = *reinterpret_cast<const u16x8*>(&hs[(size_t)s3 * C + q * 8]);
        #pragma unroll
        for (int j = 0; j < 8; ++j)
            acc[j] += (bf2f(v0[j]) + bf2f(v1[j])) + (bf2f(v2[j]) + bf2f(v3[j]));
    }
    for (; i < end; ++i) {
        int s0 = csr_src[i];
        u16x8 v0 = *reinterpret_cast<const u16x8*>(&hs[(size_t)s0 * C + q * 8]);
        #pragma unroll
        for (int j = 0; j < 8; ++j) acc[j] += bf2f(v0[j]);
    }

    float w = dinv[node];
    float4 b0 = reinterpret_cast<const float4*>(b)[q * 2];
    float4 b1 = reinterpret_cast<const float4*>(b)[q * 2 + 1];
    float bb[8] = {b0.x, b0.y, b0.z, b0.w, b1.x, b1.y, b1.z, b1.w};
    u16x8 o;
    #pragma unroll
    for (int j = 0; j < 8; ++j) {
        float v = w * acc[j] + bb[j];
        if (RELU) v = fmaxf(v, 0.0f);
        o[j] = f2bf(v);
    }
    *reinterpret_cast<u16x8*>(&outp[(size_t)node * C + q * 8]) = o;
}

// ---------------- decoder ----------------

__global__ __launch_bounds__(256) void k_decode(const int* __restrict__ esrc,
                                                const int* __restrict__ edst,
                                                const unsigned short* __restrict__ z,
                                                float* __restrict__ out) {
    int tid = threadIdx.x;
    int e = blockIdx.x * 32 + tid / 8;
    int q = tid % 8;
    if (e >= N_EDGES) return;
    int s = esrc[e], d = edst[e];
    u16x8 a = *reinterpret_cast<const u16x8*>(&z[(size_t)s * OUT_CH + q * 8]);
    u16x8 b = *reinterpret_cast<const u16x8*>(&z[(size_t)d * OUT_CH + q * 8]);
    float dot = 0.0f;
    #pragma unroll
    for (int j = 0; j < 8; ++j) dot += bf2f(a[j]) * bf2f(b[j]);
    dot += __shfl_xor(dot, 1);
    dot += __shfl_xor(dot, 2);
    dot += __shfl_xor(dot, 4);
    if (q == 0) out[e] = 1.0f / (1.0f + expf(-dot));
}

// ---------------- launch ----------------

extern "C" void kernel_launch(void* const* d_in, const int* in_sizes, int n_in,
                              void* d_out, int out_size, void* d_ws, size_t ws_size,
                              hipStream_t stream) {
    const float* x  = (const float*)d_in[0];
    const int*   ei = (const int*)d_in[1];
    const float* W1 = (const float*)d_in[2];
    const float* b1 = (const float*)d_in[3];
    const float* W2 = (const float*)d_in[4];
    const float* b2 = (const float*)d_in[5];
    float* out = (float*)d_out;

    const int* src = ei;
    const int* dst = ei + N_EDGES;

    // workspace layout (R10-proven + nodeord); overlays exploit liveness:
    //   bsorted dead after k_bucket_csr -> xb overlays it
    //   xb dead after k_gemm1 -> h1r/z overlay it
    //   hs1 dead after gather1 -> hs2 overlays it
    char* ws = (char*)d_ws;
    int*   ghist   = (int*)(ws + 0x000000);       // 1 MB
    int*   goff    = (int*)(ws + 0x100000);       // 1 MB
    int*   btot    = (int*)(ws + 0x200000);       // 4 KB
    int*   bbase   = (int*)(ws + 0x202000);       // 4.1 KB
    int*   rowoff  = (int*)(ws + 0x210000);       // 400 KB
    float* dinv    = (float*)(ws + 0x290000);     // 400 KB
    unsigned short* Wf1 = (unsigned short*)(ws + 0x310000);   // 64 KB frag-linear
    unsigned short* Wf2 = (unsigned short*)(ws + 0x320000);   // 16 KB frag-linear
    int*   nodeord = (int*)(ws + 0x330000);       // 400 KB (100096 ints)
    int*   csr_src = (int*)(ws + 0x400000);       // 6.4 MB
    int2*  bsorted = (int2*)(ws + 0xB00000);      // 12.8 MB (dead after CSR build)
    unsigned short* xb  = (unsigned short*)(ws + 0xB00000);   // 51.2 MB (dead after gemm1)
    unsigned short* hs1 = (unsigned short*)(ws + 0x3C00000);  // 25.6 MB
    unsigned short* h1r = (unsigned short*)(ws + 0xB00000);   // 25.6 MB (over dead xb)
    unsigned short* hs2 = (unsigned short*)(ws + 0x3C00000);  // 12.8 MB (over dead hs1)
    unsigned short* z   = (unsigned short*)(ws + 0x2800000);  // 12.8 MB (over dead xb tail)

    // --- CSR build (no global atomics) + degree-rank permutation ---
    k_hist<<<NPART, 256, 0, stream>>>(dst, ghist);
    k_scan_cols<<<NB, 256, 0, stream>>>(ghist, goff, btot);
    k_scan_base<<<1, NB, 0, stream>>>(btot, bbase);
    k_partition<<<NPART, 256, 0, stream>>>(src, dst, goff, bbase, bsorted);
    k_bucket_csr<<<NB_USED, 256, 0, stream>>>(bsorted, bbase, rowoff, dinv, csr_src, nodeord);

    // --- x cast + weight fragment layout ---
    k_cast<<<2048, 256, 0, stream>>>(x, xb);
    k_wt1<<<16, 256, 0, stream>>>(W1, Wf1);
    k_wt2<<<4, 256, 0, stream>>>(W2, Wf2);

    // --- layer 1 ---
    k_gemm1<<<NTILES, 256, 0, stream>>>(xb, Wf1, dinv, hs1);
    k_gather_agg<HID_CH, true><<<NORD / 16, 256, 0, stream>>>(
        nodeord, rowoff, csr_src, hs1, dinv, b1, h1r);

    // --- layer 2 ---
    k_gemm2<<<NTILES, 256, 0, stream>>>(h1r, Wf2, dinv, hs2);
    k_gather_agg<OUT_CH, false><<<NORD / 32, 256, 0, stream>>>(
        nodeord, rowoff, csr_src, hs2, dinv, b2, z);

    // --- decoder ---
    k_decode<<<N_EDGES / 32, 256, 0, stream>>>(src, dst, z, out);
}

// Round 16
// 254.444 us; speedup vs baseline: 1.1185x; 1.1065x over previous
//
#include <hip/hip_runtime.h>
#include <math.h>

#define N_NODES 100000
#define N_EDGES 1600000
#define IN_CH 256
#define HID_CH 128
#define OUT_CH 64
#define NTILES ((N_NODES + 63) / 64)     // 1563 m-tiles of 64 rows
#define NB 1024                          // buckets: node >> 7
#define NPART 256                        // partition blocks
#define EPB (N_EDGES / NPART)            // 6250 edges per partition block
#define NB_USED ((N_NODES + 127) / 128)  // 782 buckets

typedef short s16x8 __attribute__((ext_vector_type(8)));
typedef unsigned short u16x8 __attribute__((ext_vector_type(8)));
typedef float f32x4 __attribute__((ext_vector_type(4)));

__device__ __forceinline__ float bf2f(unsigned short u) {
    union { unsigned int i; float f; } v;
    v.i = ((unsigned int)u) << 16;
    return v.f;
}
__device__ __forceinline__ unsigned short f2bf(float f) {
    union { float f; unsigned int i; } v;
    v.f = f;
    unsigned int u = v.i;
    return (unsigned short)((u + 0x7FFFu + ((u >> 16) & 1u)) >> 16);  // RNE
}

// ---------------- CSR build: LDS-histogram radix partition (no global atomics) ----------------
// Partition records are PACKED: (src << 7) | (dst & 127)  — src<2^17, fits 24 bits.

__global__ __launch_bounds__(256) void k_hist(const int* __restrict__ dst,
                                              int* __restrict__ ghist) {
    __shared__ int h[NB];
    int b = blockIdx.x, t = threadIdx.x;
    for (int k = t; k < NB; k += 256) h[k] = 0;
    __syncthreads();
    int e0 = b * EPB;
    for (int e = e0 + t; e < e0 + EPB; e += 256)
        atomicAdd(&h[dst[e] >> 7], 1);
    __syncthreads();
    for (int k = t; k < NB; k += 256) ghist[k * NPART + b] = h[k];
}

__global__ __launch_bounds__(256) void k_scan_cols(const int* __restrict__ ghist,
                                                   int* __restrict__ goff,
                                                   int* __restrict__ btot) {
    __shared__ int tmp[NPART];
    int k = blockIdx.x, t = threadIdx.x;
    int v = ghist[k * NPART + t];
    tmp[t] = v;
    __syncthreads();
    for (int off = 1; off < NPART; off <<= 1) {
        int u = (t >= off) ? tmp[t - off] : 0;
        __syncthreads();
        tmp[t] += u;
        __syncthreads();
    }
    goff[k * NPART + t] = tmp[t] - v;
    if (t == NPART - 1) btot[k] = tmp[t];
}

__global__ __launch_bounds__(1024) void k_scan_base(const int* __restrict__ btot,
                                                    int* __restrict__ bbase) {
    __shared__ int tmp[NB];
    int t = threadIdx.x;
    int v = btot[t];
    tmp[t] = v;
    __syncthreads();
    for (int off = 1; off < NB; off <<= 1) {
        int u = (t >= off) ? tmp[t - off] : 0;
        __syncthreads();
        tmp[t] += u;
        __syncthreads();
    }
    bbase[t] = tmp[t] - v;
    if (t == NB - 1) bbase[NB] = tmp[t];
}

__global__ __launch_bounds__(256) void k_partition(const int* __restrict__ src,
                                                   const int* __restrict__ dst,
                                                   const int* __restrict__ goff,
                                                   const int* __restrict__ bbase,
                                                   int* __restrict__ bsorted_p) {
    __shared__ int cur[NB];
    int b = blockIdx.x, t = threadIdx.x;
    for (int k = t; k < NB; k += 256) cur[k] = bbase[k] + goff[k * NPART + b];
    __syncthreads();
    int e0 = b * EPB;
    for (int e = e0 + t; e < e0 + EPB; e += 256) {
        int s = src[e], d = dst[e];
        int pos = atomicAdd(&cur[d >> 7], 1);
        bsorted_p[pos] = (s << 7) | (d & 127);
    }
}

__global__ __launch_bounds__(256) void k_bucket_csr(const int* __restrict__ bsorted_p,
                                                    const int* __restrict__ bbase,
                                                    int* __restrict__ rowoff,
                                                    float* __restrict__ dinv,
                                                    int* __restrict__ csr_src) {
    __shared__ int cnt[128];
    __shared__ int tmp[256];
    __shared__ int cur[128];
    int b = blockIdx.x, t = threadIdx.x;
    int ebeg = bbase[b], eend = bbase[b + 1];
    if (t < 128) cnt[t] = 0;
    __syncthreads();
    for (int e = ebeg + t; e < eend; e += 256)
        atomicAdd(&cnt[bsorted_p[e] & 127], 1);
    __syncthreads();
    int v = (t < 128) ? cnt[t] : 0;
    tmp[t] = v;
    __syncthreads();
    for (int off = 1; off < 256; off <<= 1) {
        int u = (t >= off) ? tmp[t - off] : 0;
        __syncthreads();
        tmp[t] += u;
        __syncthreads();
    }
    if (t < 128) {
        int base = ebeg + tmp[t] - v;
        cur[t] = base;
        int node = b * 128 + t;
        if (node < N_NODES) {
            rowoff[node] = base;
            dinv[node] = rsqrtf((float)v + 1.0f);
        }
    }
    __syncthreads();
    for (int e = ebeg + t; e < eend; e += 256) {
        int v2 = bsorted_p[e];
        int pos = atomicAdd(&cur[v2 & 127], 1);
        csr_src[pos] = v2 >> 7;
    }
}

// ---------------- streaming cast: xb = bf16(x), fully contiguous ----------------
__global__ __launch_bounds__(256) void k_cast(const float* __restrict__ x,
                                              unsigned short* __restrict__ xb) {
    const int total = N_NODES * IN_CH / 8;
    int stride = gridDim.x * 256;
    for (int i = blockIdx.x * 256 + threadIdx.x; i < total; i += stride) {
        f32x4 a = *reinterpret_cast<const f32x4*>(x + (size_t)i * 8);
        f32x4 b = *reinterpret_cast<const f32x4*>(x + (size_t)i * 8 + 4);
        u16x8 o;
        o[0] = f2bf(a[0]); o[1] = f2bf(a[1]); o[2] = f2bf(a[2]); o[3] = f2bf(a[3]);
        o[4] = f2bf(b[0]); o[5] = f2bf(b[1]); o[6] = f2bf(b[2]); o[7] = f2bf(b[3]);
        *reinterpret_cast<u16x8*>(xb + (size_t)i * 8) = o;
    }
}

// ---------------- W -> fragment-linear bf16 layout ----------------
__global__ void k_wt1(const float* __restrict__ W1, unsigned short* __restrict__ Wf1) {
    int u = blockIdx.x * 256 + threadIdx.x;
    int f = u >> 6, lane = u & 63;
    int kk = f >> 3, nt = f & 7;
    int l15 = lane & 15, lhi = lane >> 4;
    int n = nt * 16 + l15;
    int kbase = kk * 32 + lhi * 8;
    #pragma unroll
    for (int j = 0; j < 8; ++j)
        Wf1[(size_t)u * 8 + j] = f2bf(W1[(size_t)(kbase + j) * HID_CH + n]);
}

__global__ void k_wt2(const float* __restrict__ W2, unsigned short* __restrict__ Wf2) {
    int u = blockIdx.x * 256 + threadIdx.x;
    int f = u >> 6, lane = u & 63;
    int kk = f >> 2, nt = f & 3;
    int l15 = lane & 15, lhi = lane >> 4;
    int n = nt * 16 + l15;
    int kbase = kk * 32 + lhi * 8;
    #pragma unroll
    for (int j = 0; j < 8; ++j)
        Wf2[(size_t)u * 8 + j] = f2bf(W2[(size_t)(kbase + j) * OUT_CH + n]);
}

// ---------------- GEMM1: hs1[m][n] = bf16( dinv[m] * sum_k xb[m][k] W1[k][n] ) ----------------
__global__ __launch_bounds__(256, 4) void k_gemm1(const unsigned short* __restrict__ xb,
                                                  const unsigned short* __restrict__ Wf1,
                                                  const float* __restrict__ dinv,
                                                  unsigned short* __restrict__ hs1) {
    int tid = threadIdx.x;
    int w = tid >> 6;
    int lane = tid & 63;
    int l15 = lane & 15;
    int lhi = lane >> 4;
    int m0 = blockIdx.x * 64;

    int arow = m0 + w * 16 + l15;
    int arowc = (arow < N_NODES) ? arow : (N_NODES - 1);
    const s16x8* ap = reinterpret_cast<const s16x8*>(xb + (size_t)arowc * IN_CH) + lhi;

    s16x8 af[8];
    #pragma unroll
    for (int kk = 0; kk < 8; ++kk) af[kk] = ap[kk * 4];

    const s16x8* wp = reinterpret_cast<const s16x8*>(Wf1) + lane;

    f32x4 acc[8] = {};
    #pragma unroll
    for (int kk = 0; kk < 8; ++kk) {
        #pragma unroll
        for (int nt = 0; nt < 8; ++nt) {
            s16x8 bf = wp[(kk * 8 + nt) * 64];
            acc[nt] = __builtin_amdgcn_mfma_f32_16x16x32_bf16(af[kk], bf, acc[nt], 0, 0, 0);
        }
    }

    float dv[4];
    int rb = m0 + w * 16 + lhi * 4;
    #pragma unroll
    for (int r = 0; r < 4; ++r) dv[r] = (rb + r < N_NODES) ? dinv[rb + r] : 0.0f;
    #pragma unroll
    for (int nt = 0; nt < 8; ++nt) {
        #pragma unroll
        for (int r = 0; r < 4; ++r) {
            int row = rb + r;
            if (row < N_NODES)
                hs1[(size_t)row * HID_CH + nt * 16 + l15] = f2bf(dv[r] * acc[nt][r]);
        }
    }
}

// ---------------- GEMM2: hs2[m][n] = bf16( dinv[m] * sum_k h1r[m][k] W2[k][n] ) ----------------
__global__ __launch_bounds__(256, 4) void k_gemm2(const unsigned short* __restrict__ h1r,
                                                  const unsigned short* __restrict__ Wf2,
                                                  const float* __restrict__ dinv,
                                                  unsigned short* __restrict__ hs2) {
    int tid = threadIdx.x;
    int w = tid >> 6;
    int lane = tid & 63;
    int l15 = lane & 15;
    int lhi = lane >> 4;
    int m0 = blockIdx.x * 64;

    int arow = m0 + w * 16 + l15;
    int arowc = (arow < N_NODES) ? arow : (N_NODES - 1);
    const s16x8* ap = reinterpret_cast<const s16x8*>(h1r + (size_t)arowc * HID_CH) + lhi;

    s16x8 af[4];
    #pragma unroll
    for (int kk = 0; kk < 4; ++kk) af[kk] = ap[kk * 4];

    const s16x8* wp = reinterpret_cast<const s16x8*>(Wf2) + lane;

    f32x4 acc[4] = {};
    #pragma unroll
    for (int kk = 0; kk < 4; ++kk) {
        #pragma unroll
        for (int nt = 0; nt < 4; ++nt) {
            s16x8 bf = wp[(kk * 4 + nt) * 64];
            acc[nt] = __builtin_amdgcn_mfma_f32_16x16x32_bf16(af[kk], bf, acc[nt], 0, 0, 0);
        }
    }

    float dv[4];
    int rb = m0 + w * 16 + lhi * 4;
    #pragma unroll
    for (int r = 0; r < 4; ++r) dv[r] = (rb + r < N_NODES) ? dinv[rb + r] : 0.0f;
    #pragma unroll
    for (int nt = 0; nt < 4; ++nt) {
        #pragma unroll
        for (int r = 0; r < 4; ++r) {
            int row = rb + r;
            if (row < N_NODES)
                hs2[(size_t)row * OUT_CH + nt * 16 + l15] = f2bf(dv[r] * acc[nt][r]);
        }
    }
}

// ---------------- gather aggregation (R10-proven straight order, unroll-4) ----------------
template <int C, bool RELU>
__global__ __launch_bounds__(256) void k_gather_agg(const int* __restrict__ rowoff,
                                                    const int* __restrict__ csr_src,
                                                    const unsigned short* __restrict__ hs,
                                                    const float* __restrict__ dinv,
                                                    const float* __restrict__ b,
                                                    unsigned short* __restrict__ outp) {
    constexpr int TPN = C / 8;
    constexpr int NPB = 256 / TPN;
    int t = threadIdx.x;
    int node = blockIdx.x * NPB + t / TPN;
    int q = t % TPN;
    if (node >= N_NODES) return;

    int beg = rowoff[node];
    int end = (node + 1 < N_NODES) ? rowoff[node + 1] : N_EDGES;

    float acc[8];
    {
        u16x8 sv = *reinterpret_cast<const u16x8*>(&hs[(size_t)node * C + q * 8]);
        #pragma unroll
        for (int j = 0; j < 8; ++j) acc[j] = bf2f(sv[j]);
    }

    int i = beg;
    for (; i + 3 < end; i += 4) {
        int s0 = csr_src[i], s1 = csr_src[i + 1], s2 = csr_src[i + 2], s3 = csr_src[i + 3];
        u16x8 v0 = *reinterpret_cast<const u16x8*>(&hs[(size_t)s0 * C + q * 8]);
        u16x8 v1 = *reinterpret_cast<const u16x8*>(&hs[(size_t)s1 * C + q * 8]);
        u16x8 v2 = *reinterpret_cast<const u16x8*>(&hs[(size_t)s2 * C + q * 8]);
        u16x8 v3 = *reinterpret_cast<const u16x8*>(&hs[(size_t)s3 * C + q * 8]);
        #pragma unroll
        for (int j = 0; j < 8; ++j)
            acc[j] += (bf2f(v0[j]) + bf2f(v1[j])) + (bf2f(v2[j]) + bf2f(v3[j]));
    }
    for (; i < end; ++i) {
        int s0 = csr_src[i];
        u16x8 v0 = *reinterpret_cast<const u16x8*>(&hs[(size_t)s0 * C + q * 8]);
        #pragma unroll
        for (int j = 0; j < 8; ++j) acc[j] += bf2f(v0[j]);
    }

    float w = dinv[node];
    float4 b0 = reinterpret_cast<const float4*>(b)[q * 2];
    float4 b1 = reinterpret_cast<const float4*>(b)[q * 2 + 1];
    float bb[8] = {b0.x, b0.y, b0.z, b0.w, b1.x, b1.y, b1.z, b1.w};
    u16x8 o;
    #pragma unroll
    for (int j = 0; j < 8; ++j) {
        float v = w * acc[j] + bb[j];
        if (RELU) v = fmaxf(v, 0.0f);
        o[j] = f2bf(v);
    }
    *reinterpret_cast<u16x8*>(&outp[(size_t)node * C + q * 8]) = o;
}

// ---------------- decoder ----------------

__global__ __launch_bounds__(256) void k_decode(const int* __restrict__ esrc,
                                                const int* __restrict__ edst,
                                                const unsigned short* __restrict__ z,
                                                float* __restrict__ out) {
    int tid = threadIdx.x;
    int e = blockIdx.x * 32 + tid / 8;
    int q = tid % 8;
    if (e >= N_EDGES) return;
    int s = esrc[e], d = edst[e];
    u16x8 a = *reinterpret_cast<const u16x8*>(&z[(size_t)s * OUT_CH + q * 8]);
    u16x8 b = *reinterpret_cast<const u16x8*>(&z[(size_t)d * OUT_CH + q * 8]);
    float dot = 0.0f;
    #pragma unroll
    for (int j = 0; j < 8; ++j) dot += bf2f(a[j]) * bf2f(b[j]);
    dot += __shfl_xor(dot, 1);
    dot += __shfl_xor(dot, 2);
    dot += __shfl_xor(dot, 4);
    if (q == 0) out[e] = 1.0f / (1.0f + expf(-dot));
}

// ---------------- launch ----------------

extern "C" void kernel_launch(void* const* d_in, const int* in_sizes, int n_in,
                              void* d_out, int out_size, void* d_ws, size_t ws_size,
                              hipStream_t stream) {
    const float* x  = (const float*)d_in[0];
    const int*   ei = (const int*)d_in[1];
    const float* W1 = (const float*)d_in[2];
    const float* b1 = (const float*)d_in[3];
    const float* W2 = (const float*)d_in[4];
    const float* b2 = (const float*)d_in[5];
    float* out = (float*)d_out;

    const int* src = ei;
    const int* dst = ei + N_EDGES;

    // workspace layout; overlays exploit liveness:
    //   bsorted_p dead after k_bucket_csr -> xb overlays it
    //   xb dead after k_gemm1 -> h1r/z overlay it
    //   hs1 dead after gather1 -> hs2 overlays it
    char* ws = (char*)d_ws;
    int*   ghist   = (int*)(ws + 0x000000);       // 1 MB
    int*   goff    = (int*)(ws + 0x100000);       // 1 MB
    int*   btot    = (int*)(ws + 0x200000);       // 4 KB
    int*   bbase   = (int*)(ws + 0x202000);       // 4.1 KB
    int*   rowoff  = (int*)(ws + 0x210000);       // 400 KB
    float* dinv    = (float*)(ws + 0x290000);     // 400 KB
    unsigned short* Wf1 = (unsigned short*)(ws + 0x310000);   // 64 KB frag-linear
    unsigned short* Wf2 = (unsigned short*)(ws + 0x320000);   // 16 KB frag-linear
    int*   csr_src = (int*)(ws + 0x400000);       // 6.4 MB
    int*   bsorted_p = (int*)(ws + 0xB00000);     // 6.4 MB packed (dead after CSR build)
    unsigned short* xb  = (unsigned short*)(ws + 0xB00000);   // 51.2 MB (dead after gemm1)
    unsigned short* hs1 = (unsigned short*)(ws + 0x3C00000);  // 25.6 MB
    unsigned short* h1r = (unsigned short*)(ws + 0xB00000);   // 25.6 MB (over dead xb)
    unsigned short* hs2 = (unsigned short*)(ws + 0x3C00000);  // 12.8 MB (over dead hs1)
    unsigned short* z   = (unsigned short*)(ws + 0x2800000);  // 12.8 MB (over dead xb tail)

    // --- CSR build (no global atomics, packed records) ---
    k_hist<<<NPART, 256, 0, stream>>>(dst, ghist);
    k_scan_cols<<<NB, 256, 0, stream>>>(ghist, goff, btot);
    k_scan_base<<<1, NB, 0, stream>>>(btot, bbase);
    k_partition<<<NPART, 256, 0, stream>>>(src, dst, goff, bbase, bsorted_p);
    k_bucket_csr<<<NB_USED, 256, 0, stream>>>(bsorted_p, bbase, rowoff, dinv, csr_src);

    // --- x cast + weight fragment layout ---
    k_cast<<<2048, 256, 0, stream>>>(x, xb);
    k_wt1<<<16, 256, 0, stream>>>(W1, Wf1);
    k_wt2<<<4, 256, 0, stream>>>(W2, Wf2);

    // --- layer 1 ---
    k_gemm1<<<NTILES, 256, 0, stream>>>(xb, Wf1, dinv, hs1);
    k_gather_agg<HID_CH, true><<<(N_NODES * 16 + 255) / 256, 256, 0, stream>>>(
        rowoff, csr_src, hs1, dinv, b1, h1r);

    // --- layer 2 ---
    k_gemm2<<<NTILES, 256, 0, stream>>>(h1r, Wf2, dinv, hs2);
    k_gather_agg<OUT_CH, false><<<(N_NODES * 8 + 255) / 256, 256, 0, stream>>>(
        rowoff, csr_src, hs2, dinv, b2, z);

    // --- decoder ---
    k_decode<<<N_EDGES / 32, 256, 0, stream>>>(src, dst, z, out);
}

// Round 17
// 238.877 us; speedup vs baseline: 1.1914x; 1.0652x over previous
//
#include <hip/hip_runtime.h>
#include <math.h>

#define N_NODES 100000
#define N_EDGES 1600000
#define IN_CH 256
#define HID_CH 128
#define OUT_CH 64
#define NTILES ((N_NODES + 63) / 64)     // 1563 m-tiles of 64 rows
#define NB 1024                          // buckets: node >> 7
#define NPART 256                        // partition blocks
#define EPB (N_EDGES / NPART)            // 6250 edges per partition block
#define NB_USED ((N_NODES + 127) / 128)  // 782 buckets
#define CAST_BLKS 2048

typedef short s16x8 __attribute__((ext_vector_type(8)));
typedef unsigned short u16x8 __attribute__((ext_vector_type(8)));
typedef float f32x4 __attribute__((ext_vector_type(4)));

__device__ __forceinline__ float bf2f(unsigned short u) {
    union { unsigned int i; float f; } v;
    v.i = ((unsigned int)u) << 16;
    return v.f;
}
__device__ __forceinline__ unsigned short f2bf(float f) {
    union { float f; unsigned int i; } v;
    v.f = f;
    unsigned int u = v.i;
    return (unsigned short)((u + 0x7FFFu + ((u >> 16) & 1u)) >> 16);  // RNE
}

// ================= K1: fused {cast || hist || wt1 || wt2} =================
// All four are mutually independent; packing them into one grid lets them
// co-execute (single stream would otherwise serialize).

__device__ __forceinline__ void role_cast(int b, const float* __restrict__ x,
                                          unsigned short* __restrict__ xb) {
    const int total = N_NODES * IN_CH / 8;
    int stride = CAST_BLKS * 256;
    for (int i = b * 256 + threadIdx.x; i < total; i += stride) {
        f32x4 a = *reinterpret_cast<const f32x4*>(x + (size_t)i * 8);
        f32x4 c = *reinterpret_cast<const f32x4*>(x + (size_t)i * 8 + 4);
        u16x8 o;
        o[0] = f2bf(a[0]); o[1] = f2bf(a[1]); o[2] = f2bf(a[2]); o[3] = f2bf(a[3]);
        o[4] = f2bf(c[0]); o[5] = f2bf(c[1]); o[6] = f2bf(c[2]); o[7] = f2bf(c[3]);
        *reinterpret_cast<u16x8*>(xb + (size_t)i * 8) = o;
    }
}

__global__ __launch_bounds__(256) void k_fused_pre(const float* __restrict__ x,
                                                   const int* __restrict__ dst,
                                                   const float* __restrict__ W1,
                                                   const float* __restrict__ W2,
                                                   unsigned short* __restrict__ xb,
                                                   int* __restrict__ ghist,
                                                   unsigned short* __restrict__ Wf1,
                                                   unsigned short* __restrict__ Wf2) {
    __shared__ int h[NB];
    int b = blockIdx.x, t = threadIdx.x;
    if (b < CAST_BLKS) {
        role_cast(b, x, xb);
    } else if (b < CAST_BLKS + NPART) {
        int hb = b - CAST_BLKS;
        for (int k = t; k < NB; k += 256) h[k] = 0;
        __syncthreads();
        int e0 = hb * EPB;
        for (int e = e0 + t; e < e0 + EPB; e += 256)
            atomicAdd(&h[dst[e] >> 7], 1);
        __syncthreads();
        for (int k = t; k < NB; k += 256) ghist[k * NPART + hb] = h[k];
    } else if (b < CAST_BLKS + NPART + 16) {
        int u = (b - CAST_BLKS - NPART) * 256 + t;  // 4096 units
        int f = u >> 6, lane = u & 63;
        int kk = f >> 3, nt = f & 7;
        int l15 = lane & 15, lhi = lane >> 4;
        int n = nt * 16 + l15;
        int kbase = kk * 32 + lhi * 8;
        #pragma unroll
        for (int j = 0; j < 8; ++j)
            Wf1[(size_t)u * 8 + j] = f2bf(W1[(size_t)(kbase + j) * HID_CH + n]);
    } else {
        int u = (b - CAST_BLKS - NPART - 16) * 256 + t;  // 1024 units
        int f = u >> 6, lane = u & 63;
        int kk = f >> 2, nt = f & 3;
        int l15 = lane & 15, lhi = lane >> 4;
        int n = nt * 16 + l15;
        int kbase = kk * 32 + lhi * 8;
        #pragma unroll
        for (int j = 0; j < 8; ++j)
            Wf2[(size_t)u * 8 + j] = f2bf(W2[(size_t)(kbase + j) * OUT_CH + n]);
    }
}

// ================= scans =================

__global__ __launch_bounds__(256) void k_scan_cols(const int* __restrict__ ghist,
                                                   int* __restrict__ goff,
                                                   int* __restrict__ btot) {
    __shared__ int tmp[NPART];
    int k = blockIdx.x, t = threadIdx.x;
    int v = ghist[k * NPART + t];
    tmp[t] = v;
    __syncthreads();
    for (int off = 1; off < NPART; off <<= 1) {
        int u = (t >= off) ? tmp[t - off] : 0;
        __syncthreads();
        tmp[t] += u;
        __syncthreads();
    }
    goff[k * NPART + t] = tmp[t] - v;
    if (t == NPART - 1) btot[k] = tmp[t];
}

__global__ __launch_bounds__(1024) void k_scan_base(const int* __restrict__ btot,
                                                    int* __restrict__ bbase) {
    __shared__ int tmp[NB];
    int t = threadIdx.x;
    int v = btot[t];
    tmp[t] = v;
    __syncthreads();
    for (int off = 1; off < NB; off <<= 1) {
        int u = (t >= off) ? tmp[t - off] : 0;
        __syncthreads();
        tmp[t] += u;
        __syncthreads();
    }
    bbase[t] = tmp[t] - v;
    if (t == NB - 1) bbase[NB] = tmp[t];
}

// ================= K3: fused {partition || gemm1 (dinv-free)} =================
// partition depends on scans; gemm1 depends only on xb/Wf1 (dinv folded into gather1).

__global__ __launch_bounds__(256) void k_fused_mid(const int* __restrict__ src,
                                                   const int* __restrict__ dst,
                                                   const int* __restrict__ goff,
                                                   const int* __restrict__ bbase,
                                                   int* __restrict__ bsorted_p,
                                                   const unsigned short* __restrict__ xb,
                                                   const unsigned short* __restrict__ Wf1,
                                                   unsigned short* __restrict__ h1) {
    __shared__ int cur[NB];
    int b = blockIdx.x, t = threadIdx.x;
    if (b < NPART) {
        // ---- partition role ----
        for (int k = t; k < NB; k += 256) cur[k] = bbase[k] + goff[k * NPART + b];
        __syncthreads();
        int e0 = b * EPB;
        for (int e = e0 + t; e < e0 + EPB; e += 256) {
            int s = src[e], d = dst[e];
            int pos = atomicAdd(&cur[d >> 7], 1);
            bsorted_p[pos] = (s << 7) | (d & 127);
        }
    } else {
        // ---- gemm1 role: h1[m][n] = bf16( sum_k xb[m][k] W1[k][n] ), NO dinv ----
        int mt = b - NPART;
        int w = t >> 6;
        int lane = t & 63;
        int l15 = lane & 15;
        int lhi = lane >> 4;
        int m0 = mt * 64;

        int arow = m0 + w * 16 + l15;
        int arowc = (arow < N_NODES) ? arow : (N_NODES - 1);
        const s16x8* ap = reinterpret_cast<const s16x8*>(xb + (size_t)arowc * IN_CH) + lhi;

        s16x8 af[8];
        #pragma unroll
        for (int kk = 0; kk < 8; ++kk) af[kk] = ap[kk * 4];

        const s16x8* wp = reinterpret_cast<const s16x8*>(Wf1) + lane;

        f32x4 acc[8] = {};
        #pragma unroll
        for (int kk = 0; kk < 8; ++kk) {
            #pragma unroll
            for (int nt = 0; nt < 8; ++nt) {
                s16x8 bf = wp[(kk * 8 + nt) * 64];
                acc[nt] = __builtin_amdgcn_mfma_f32_16x16x32_bf16(af[kk], bf, acc[nt], 0, 0, 0);
            }
        }

        int rb = m0 + w * 16 + lhi * 4;
        #pragma unroll
        for (int nt = 0; nt < 8; ++nt) {
            #pragma unroll
            for (int r = 0; r < 4; ++r) {
                int row = rb + r;
                if (row < N_NODES)
                    h1[(size_t)row * HID_CH + nt * 16 + l15] = f2bf(acc[nt][r]);
            }
        }
    }
}

// ================= bucket CSR =================

__global__ __launch_bounds__(256) void k_bucket_csr(const int* __restrict__ bsorted_p,
                                                    const int* __restrict__ bbase,
                                                    int* __restrict__ rowoff,
                                                    float* __restrict__ dinv,
                                                    int* __restrict__ csr_src) {
    __shared__ int cnt[128];
    __shared__ int tmp[256];
    __shared__ int cur[128];
    int b = blockIdx.x, t = threadIdx.x;
    int ebeg = bbase[b], eend = bbase[b + 1];
    if (t < 128) cnt[t] = 0;
    __syncthreads();
    for (int e = ebeg + t; e < eend; e += 256)
        atomicAdd(&cnt[bsorted_p[e] & 127], 1);
    __syncthreads();
    int v = (t < 128) ? cnt[t] : 0;
    tmp[t] = v;
    __syncthreads();
    for (int off = 1; off < 256; off <<= 1) {
        int u = (t >= off) ? tmp[t - off] : 0;
        __syncthreads();
        tmp[t] += u;
        __syncthreads();
    }
    if (t < 128) {
        int base = ebeg + tmp[t] - v;
        cur[t] = base;
        int node = b * 128 + t;
        if (node < N_NODES) {
            rowoff[node] = base;
            dinv[node] = rsqrtf((float)v + 1.0f);
        }
    }
    __syncthreads();
    for (int e = ebeg + t; e < eend; e += 256) {
        int v2 = bsorted_p[e];
        int pos = atomicAdd(&cur[v2 & 127], 1);
        csr_src[pos] = v2 >> 7;
    }
}

// ================= gather1: dinv folded (h1 is un-normalized) =================
// out[d] = relu( dinv_d*(dinv_d*h1[d] + sum_s dinv_s*h1[s]) + b1 )
__global__ __launch_bounds__(256) void k_gather1(const int* __restrict__ rowoff,
                                                 const int* __restrict__ csr_src,
                                                 const unsigned short* __restrict__ h1,
                                                 const float* __restrict__ dinv,
                                                 const float* __restrict__ b,
                                                 unsigned short* __restrict__ outp) {
    int t = threadIdx.x;
    int node = blockIdx.x * 16 + t / 16;
    int q = t % 16;
    if (node >= N_NODES) return;

    int beg = rowoff[node];
    int end = (node + 1 < N_NODES) ? rowoff[node + 1] : N_EDGES;
    float wd = dinv[node];

    float acc[8];
    {
        u16x8 sv = *reinterpret_cast<const u16x8*>(&h1[(size_t)node * HID_CH + q * 8]);
        #pragma unroll
        for (int j = 0; j < 8; ++j) acc[j] = wd * bf2f(sv[j]);
    }

    int i = beg;
    for (; i + 3 < end; i += 4) {
        int s0 = csr_src[i], s1 = csr_src[i + 1], s2 = csr_src[i + 2], s3 = csr_src[i + 3];
        float d0 = dinv[s0], d1 = dinv[s1], d2 = dinv[s2], d3 = dinv[s3];
        u16x8 v0 = *reinterpret_cast<const u16x8*>(&h1[(size_t)s0 * HID_CH + q * 8]);
        u16x8 v1 = *reinterpret_cast<const u16x8*>(&h1[(size_t)s1 * HID_CH + q * 8]);
        u16x8 v2 = *reinterpret_cast<const u16x8*>(&h1[(size_t)s2 * HID_CH + q * 8]);
        u16x8 v3 = *reinterpret_cast<const u16x8*>(&h1[(size_t)s3 * HID_CH + q * 8]);
        #pragma unroll
        for (int j = 0; j < 8; ++j)
            acc[j] += (d0 * bf2f(v0[j]) + d1 * bf2f(v1[j])) +
                      (d2 * bf2f(v2[j]) + d3 * bf2f(v3[j]));
    }
    for (; i < end; ++i) {
        int s0 = csr_src[i];
        float d0 = dinv[s0];
        u16x8 v0 = *reinterpret_cast<const u16x8*>(&h1[(size_t)s0 * HID_CH + q * 8]);
        #pragma unroll
        for (int j = 0; j < 8; ++j) acc[j] += d0 * bf2f(v0[j]);
    }

    float4 b0 = reinterpret_cast<const float4*>(b)[q * 2];
    float4 b1 = reinterpret_cast<const float4*>(b)[q * 2 + 1];
    float bb[8] = {b0.x, b0.y, b0.z, b0.w, b1.x, b1.y, b1.z, b1.w};
    u16x8 o;
    #pragma unroll
    for (int j = 0; j < 8; ++j)
        o[j] = f2bf(fmaxf(wd * acc[j] + bb[j], 0.0f));
    *reinterpret_cast<u16x8*>(&outp[(size_t)node * HID_CH + q * 8]) = o;
}

// ================= GEMM2 (dinv epilogue, unchanged) =================
__global__ __launch_bounds__(256, 4) void k_gemm2(const unsigned short* __restrict__ h1r,
                                                  const unsigned short* __restrict__ Wf2,
                                                  const float* __restrict__ dinv,
                                                  unsigned short* __restrict__ hs2) {
    int tid = threadIdx.x;
    int w = tid >> 6;
    int lane = tid & 63;
    int l15 = lane & 15;
    int lhi = lane >> 4;
    int m0 = blockIdx.x * 64;

    int arow = m0 + w * 16 + l15;
    int arowc = (arow < N_NODES) ? arow : (N_NODES - 1);
    const s16x8* ap = reinterpret_cast<const s16x8*>(h1r + (size_t)arowc * HID_CH) + lhi;

    s16x8 af[4];
    #pragma unroll
    for (int kk = 0; kk < 4; ++kk) af[kk] = ap[kk * 4];

    const s16x8* wp = reinterpret_cast<const s16x8*>(Wf2) + lane;

    f32x4 acc[4] = {};
    #pragma unroll
    for (int kk = 0; kk < 4; ++kk) {
        #pragma unroll
        for (int nt = 0; nt < 4; ++nt) {
            s16x8 bf = wp[(kk * 4 + nt) * 64];
            acc[nt] = __builtin_amdgcn_mfma_f32_16x16x32_bf16(af[kk], bf, acc[nt], 0, 0, 0);
        }
    }

    float dv[4];
    int rb = m0 + w * 16 + lhi * 4;
    #pragma unroll
    for (int r = 0; r < 4; ++r) dv[r] = (rb + r < N_NODES) ? dinv[rb + r] : 0.0f;
    #pragma unroll
    for (int nt = 0; nt < 4; ++nt) {
        #pragma unroll
        for (int r = 0; r < 4; ++r) {
            int row = rb + r;
            if (row < N_NODES)
                hs2[(size_t)row * OUT_CH + nt * 16 + l15] = f2bf(dv[r] * acc[nt][r]);
        }
    }
}

// ================= gather2 (standard, unchanged from R16) =================
template <int C, bool RELU>
__global__ __launch_bounds__(256) void k_gather_agg(const int* __restrict__ rowoff,
                                                    const int* __restrict__ csr_src,
                                                    const unsigned short* __restrict__ hs,
                                                    const float* __restrict__ dinv,
                                                    const float* __restrict__ b,
                                                    unsigned short* __restrict__ outp) {
    constexpr int TPN = C / 8;
    constexpr int NPB = 256 / TPN;
    int t = threadIdx.x;
    int node = blockIdx.x * NPB + t / TPN;
    int q = t % TPN;
    if (node >= N_NODES) return;

    int beg = rowoff[node];
    int end = (node + 1 < N_NODES) ? rowoff[node + 1] : N_EDGES;

    float acc[8];
    {
        u16x8 sv = *reinterpret_cast<const u16x8*>(&hs[(size_t)node * C + q * 8]);
        #pragma unroll
        for (int j = 0; j < 8; ++j) acc[j] = bf2f(sv[j]);
    }

    int i = beg;
    for (; i + 3 < end; i += 4) {
        int s0 = csr_src[i], s1 = csr_src[i + 1], s2 = csr_src[i + 2], s3 = csr_src[i + 3];
        u16x8 v0 = *reinterpret_cast<const u16x8*>(&hs[(size_t)s0 * C + q * 8]);
        u16x8 v1 = *reinterpret_cast<const u16x8*>(&hs[(size_t)s1 * C + q * 8]);
        u16x8 v2 = *reinterpret_cast<const u16x8*>(&hs[(size_t)s2 * C + q * 8]);
        u16x8 v3 = *reinterpret_cast<const u16x8*>(&hs[(size_t)s3 * C + q * 8]);
        #pragma unroll
        for (int j = 0; j < 8; ++j)
            acc[j] += (bf2f(v0[j]) + bf2f(v1[j])) + (bf2f(v2[j]) + bf2f(v3[j]));
    }
    for (; i < end; ++i) {
        int s0 = csr_src[i];
        u16x8 v0 = *reinterpret_cast<const u16x8*>(&hs[(size_t)s0 * C + q * 8]);
        #pragma unroll
        for (int j = 0; j < 8; ++j) acc[j] += bf2f(v0[j]);
    }

    float w = dinv[node];
    float4 b0 = reinterpret_cast<const float4*>(b)[q * 2];
    float4 b1 = reinterpret_cast<const float4*>(b)[q * 2 + 1];
    float bb[8] = {b0.x, b0.y, b0.z, b0.w, b1.x, b1.y, b1.z, b1.w};
    u16x8 o;
    #pragma unroll
    for (int j = 0; j < 8; ++j) {
        float v = w * acc[j] + bb[j];
        if (RELU) v = fmaxf(v, 0.0f);
        o[j] = f2bf(v);
    }
    *reinterpret_cast<u16x8*>(&outp[(size_t)node * C + q * 8]) = o;
}

// ================= decoder =================

__global__ __launch_bounds__(256) void k_decode(const int* __restrict__ esrc,
                                                const int* __restrict__ edst,
                                                const unsigned short* __restrict__ z,
                                                float* __restrict__ out) {
    int tid = threadIdx.x;
    int e = blockIdx.x * 32 + tid / 8;
    int q = tid % 8;
    if (e >= N_EDGES) return;
    int s = esrc[e], d = edst[e];
    u16x8 a = *reinterpret_cast<const u16x8*>(&z[(size_t)s * OUT_CH + q * 8]);
    u16x8 b = *reinterpret_cast<const u16x8*>(&z[(size_t)d * OUT_CH + q * 8]);
    float dot = 0.0f;
    #pragma unroll
    for (int j = 0; j < 8; ++j) dot += bf2f(a[j]) * bf2f(b[j]);
    dot += __shfl_xor(dot, 1);
    dot += __shfl_xor(dot, 2);
    dot += __shfl_xor(dot, 4);
    if (q == 0) out[e] = 1.0f / (1.0f + expf(-dot));
}

// ================= launch =================

extern "C" void kernel_launch(void* const* d_in, const int* in_sizes, int n_in,
                              void* d_out, int out_size, void* d_ws, size_t ws_size,
                              hipStream_t stream) {
    const float* x  = (const float*)d_in[0];
    const int*   ei = (const int*)d_in[1];
    const float* W1 = (const float*)d_in[2];
    const float* b1 = (const float*)d_in[3];
    const float* W2 = (const float*)d_in[4];
    const float* b2 = (const float*)d_in[5];
    float* out = (float*)d_out;

    const int* src = ei;
    const int* dst = ei + N_EDGES;

    // workspace layout (cast now precedes partition, so xb no longer overlays
    // bsorted_p). Overlays:
    //   xb dead after k_fused_mid -> h1r/hs2 overlay it
    //   h1 dead after gather1 -> z overlays it
    char* ws = (char*)d_ws;
    int*   ghist   = (int*)(ws + 0x000000);       // 1 MB
    int*   goff    = (int*)(ws + 0x100000);       // 1 MB
    int*   btot    = (int*)(ws + 0x200000);       // 4 KB
    int*   bbase   = (int*)(ws + 0x202000);       // 4.1 KB
    int*   rowoff  = (int*)(ws + 0x210000);       // 400 KB
    float* dinv    = (float*)(ws + 0x290000);     // 400 KB
    unsigned short* Wf1 = (unsigned short*)(ws + 0x310000);   // 64 KB
    unsigned short* Wf2 = (unsigned short*)(ws + 0x320000);   // 16 KB
    int*   csr_src   = (int*)(ws + 0x400000);     // 6.4 MB
    int*   bsorted_p = (int*)(ws + 0xB00000);     // 6.4 MB
    unsigned short* xb  = (unsigned short*)(ws + 0x1200000);  // 51.2 MB (dead after fused_mid)
    unsigned short* h1  = (unsigned short*)(ws + 0x4300000);  // 25.6 MB (dead after gather1)
    unsigned short* h1r = (unsigned short*)(ws + 0x1200000);  // 25.6 MB (over dead xb)
    unsigned short* hs2 = (unsigned short*)(ws + 0x2B00000);  // 12.8 MB (over dead xb tail)
    unsigned short* z   = (unsigned short*)(ws + 0x4300000);  // 12.8 MB (over dead h1)

    // K1: {cast || hist || wt1 || wt2}
    k_fused_pre<<<CAST_BLKS + NPART + 16 + 4, 256, 0, stream>>>(
        x, dst, W1, W2, xb, ghist, Wf1, Wf2);

    // scans
    k_scan_cols<<<NB, 256, 0, stream>>>(ghist, goff, btot);
    k_scan_base<<<1, NB, 0, stream>>>(btot, bbase);

    // K3: {partition || gemm1}
    k_fused_mid<<<NPART + NTILES, 256, 0, stream>>>(
        src, dst, goff, bbase, bsorted_p, xb, Wf1, h1);

    // bucket CSR (rowoff, dinv, csr_src)
    k_bucket_csr<<<NB_USED, 256, 0, stream>>>(bsorted_p, bbase, rowoff, dinv, csr_src);

    // layer 1 aggregation (dinv folded)
    k_gather1<<<(N_NODES * 16 + 255) / 256, 256, 0, stream>>>(
        rowoff, csr_src, h1, dinv, b1, h1r);

    // layer 2
    k_gemm2<<<NTILES, 256, 0, stream>>>(h1r, Wf2, dinv, hs2);
    k_gather_agg<OUT_CH, false><<<(N_NODES * 8 + 255) / 256, 256, 0, stream>>>(
        rowoff, csr_src, hs2, dinv, b2, z);

    // decoder
    k_decode<<<N_EDGES / 32, 256, 0, stream>>>(src, dst, z, out);
}